// Round 1
// baseline (3553.003 us; speedup 1.0000x reference)
//
#include <hip/hip_runtime.h>
#include <hip/hip_bf16.h>

#define T_DIM 1024
#define H_DIM 2880
#define I_DIM 2880
#define E_NUM 16
#define TOPK 4
#define ALPHA 1.702f
#define LIMIT 7.0f

typedef __attribute__((ext_vector_type(8))) short bf16x8;
typedef __attribute__((ext_vector_type(4))) float f32x4;

// ---- workspace layout (bytes) ----
#define XB_OFF    0                          // bf16 [T][H]           5,898,240
#define LIDX_OFF  5898240                    // int  [E][T]              65,536
#define LWT_OFF   5963776                    // f32  [E][T]              65,536
#define CNT_OFF   6029312                    // int  [E]                     64
#define OFF_OFF   6029376                    // int  [E]                     64
#define HBUF_OFF  6029568                    // bf16 [5120][I]       29,491,200
// total ~35.5 MB

__device__ __forceinline__ unsigned short f2bf(float f) {
    unsigned u = __float_as_uint(f);
    u += 0x7fff + ((u >> 16) & 1);           // round-to-nearest-even
    return (unsigned short)(u >> 16);
}

__device__ __forceinline__ uint4 pack8(float4 a, float4 b) {
    uint4 o;
    o.x = (unsigned)f2bf(a.x) | ((unsigned)f2bf(a.y) << 16);
    o.y = (unsigned)f2bf(a.z) | ((unsigned)f2bf(a.w) << 16);
    o.z = (unsigned)f2bf(b.x) | ((unsigned)f2bf(b.y) << 16);
    o.w = (unsigned)f2bf(b.z) | ((unsigned)f2bf(b.w) << 16);
    return o;
}

// ---------------- router: logits -> top4 -> per-expert token lists ----------
__global__ __launch_bounds__(256) void router_kernel(
    const float* __restrict__ x, const float* __restrict__ rw,
    const float* __restrict__ rb,
    int* __restrict__ list_idx, float* __restrict__ list_wt,
    int* __restrict__ counts)
{
    const int t = blockIdx.x;
    const int e = threadIdx.x >> 4;   // 0..15
    const int l = threadIdx.x & 15;
    const float* xr = x + (size_t)t * H_DIM;
    const float* wr = rw + (size_t)e * H_DIM;
    float s = 0.f;
    for (int h = l; h < H_DIM; h += 16) s += xr[h] * wr[h];
    // reduce across the 16 lanes of this expert group (contiguous in wave)
    for (int d = 8; d >= 1; d >>= 1) s += __shfl_xor(s, d, 64);
    __shared__ float logits[E_NUM];
    if (l == 0) logits[e] = s + rb[e];
    __syncthreads();
    if (threadIdx.x == 0) {
        float lv[E_NUM];
        for (int i = 0; i < E_NUM; i++) lv[i] = logits[i];
        int idx[TOPK]; float val[TOPK];
        for (int k = 0; k < TOPK; k++) {
            int bi = 0; float bv = -1e30f;
            for (int i = 0; i < E_NUM; i++)
                if (lv[i] > bv) { bv = lv[i]; bi = i; }
            idx[k] = bi; val[k] = bv; lv[bi] = -1e30f;
        }
        float m = val[0], sum = 0.f, w[TOPK];
        for (int k = 0; k < TOPK; k++) { w[k] = __expf(val[k] - m); sum += w[k]; }
        float inv = 1.f / sum;
        for (int k = 0; k < TOPK; k++) {
            int ee = idx[k];
            int pos = atomicAdd(&counts[ee], 1);
            list_idx[ee * T_DIM + pos] = t;
            list_wt[ee * T_DIM + pos] = w[k] * inv;
        }
    }
}

// ---------------- 64-padded prefix offsets --------------------------------
__global__ void offsets_kernel(const int* __restrict__ counts, int* __restrict__ offs) {
    if (threadIdx.x == 0 && blockIdx.x == 0) {
        int o = 0;
        for (int e = 0; e < E_NUM; e++) { offs[e] = o; o += (counts[e] + 63) & ~63; }
    }
}

// ---------------- fp32 -> bf16 conversion of x ----------------------------
__global__ __launch_bounds__(256) void cvt_kernel(
    const float4* __restrict__ x, uint2* __restrict__ xb)
{
    int i = blockIdx.x * 256 + threadIdx.x;   // grid sized exactly T*H/4
    float4 v = x[i];
    uint2 o;
    o.x = (unsigned)f2bf(v.x) | ((unsigned)f2bf(v.y) << 16);
    o.y = (unsigned)f2bf(v.z) | ((unsigned)f2bf(v.w) << 16);
    xb[i] = o;
}

// ---------------- gate/up GEMM + activation -> hbuf (bf16) ----------------
// grid: (m_tiles=16, n_tiles=45, E); block 256 (4 waves), tile 64x64, BK=32
__global__ __launch_bounds__(256) void gemm1_kernel(
    const unsigned short* __restrict__ xb,
    const float* __restrict__ w1, const float* __restrict__ b1,
    const float* __restrict__ w3, const float* __restrict__ b3,
    const int* __restrict__ list_idx, const int* __restrict__ counts,
    const int* __restrict__ offs, unsigned short* __restrict__ hbuf)
{
    const int e = blockIdx.z;
    const int cnt = counts[e];
    const int m0 = blockIdx.x * 64;
    if (m0 >= cnt) return;
    const int n0 = blockIdx.y * 64;
    const int off_e = offs[e];

    __shared__ unsigned short As[64 * 40];
    __shared__ unsigned short Bg[64 * 40];
    __shared__ unsigned short Bu[64 * 40];

    const int tid = threadIdx.x;
    const int r = tid >> 2;      // 0..63
    const int seg = tid & 3;     // 0..3

    int ia = m0 + r; if (ia >= cnt) ia = cnt - 1;
    const int tok = list_idx[e * T_DIM + ia];
    const unsigned short* aptr = xb + (size_t)tok * H_DIM + seg * 8;
    const float* gptr = w1 + ((size_t)e * I_DIM + n0 + r) * H_DIM + seg * 8;
    const float* uptr = w3 + ((size_t)e * I_DIM + n0 + r) * H_DIM + seg * 8;

    const int lane = tid & 63;
    const int wv = tid >> 6;
    const int wm = (wv >> 1) * 32;
    const int wn = (wv & 1) * 32;
    const int lm = lane & 15;
    const int quad = lane >> 4;
    const int koff = quad * 8;

    f32x4 accg[2][2], accu[2][2];
    for (int i = 0; i < 2; i++)
        for (int j = 0; j < 2; j++) { accg[i][j] = (f32x4)(0.f); accu[i][j] = (f32x4)(0.f); }

    for (int k0 = 0; k0 < H_DIM; k0 += 32) {
        *(uint4*)&As[r * 40 + seg * 8] = *(const uint4*)(aptr + k0);
        float4 f0 = *(const float4*)(gptr + k0);
        float4 f1 = *(const float4*)(gptr + k0 + 4);
        *(uint4*)&Bg[r * 40 + seg * 8] = pack8(f0, f1);
        float4 g0 = *(const float4*)(uptr + k0);
        float4 g1 = *(const float4*)(uptr + k0 + 4);
        *(uint4*)&Bu[r * 40 + seg * 8] = pack8(g0, g1);
        __syncthreads();

        bf16x8 af[2], bg[2], bu[2];
        for (int ms = 0; ms < 2; ms++)
            af[ms] = *(const bf16x8*)&As[(wm + ms * 16 + lm) * 40 + koff];
        for (int ns = 0; ns < 2; ns++) {
            bg[ns] = *(const bf16x8*)&Bg[(wn + ns * 16 + lm) * 40 + koff];
            bu[ns] = *(const bf16x8*)&Bu[(wn + ns * 16 + lm) * 40 + koff];
        }
        for (int ms = 0; ms < 2; ms++)
            for (int ns = 0; ns < 2; ns++) {
                accg[ms][ns] = __builtin_amdgcn_mfma_f32_16x16x32_bf16(af[ms], bg[ns], accg[ms][ns], 0, 0, 0);
                accu[ms][ns] = __builtin_amdgcn_mfma_f32_16x16x32_bf16(af[ms], bu[ns], accu[ms][ns], 0, 0, 0);
            }
        __syncthreads();
    }

    for (int ms = 0; ms < 2; ms++)
        for (int ns = 0; ns < 2; ns++)
            for (int rg = 0; rg < 4; rg++) {
                int row = wm + ms * 16 + quad * 4 + rg;   // C/D: row=(lane>>4)*4+reg
                int col = wn + ns * 16 + lm;              //      col=lane&15
                int j = n0 + col;
                float gate = accg[ms][ns][rg] + b1[e * I_DIM + j];
                float up   = accu[ms][ns][rg] + b3[e * I_DIM + j];
                gate = fminf(gate, LIMIT);
                up = fminf(fmaxf(up, -LIMIT), LIMIT);
                float act = gate / (1.f + __expf(-ALPHA * gate));
                float h = (up + 1.f) * act;
                hbuf[(size_t)(off_e + m0 + row) * I_DIM + j] = f2bf(h);
            }
}

// ---------------- down GEMM + weighted scatter-add ------------------------
__global__ __launch_bounds__(256) void gemm2_kernel(
    const unsigned short* __restrict__ hbuf,
    const float* __restrict__ w2, const float* __restrict__ b2,
    const int* __restrict__ list_idx, const float* __restrict__ list_wt,
    const int* __restrict__ counts, const int* __restrict__ offs,
    float* __restrict__ y)
{
    const int e = blockIdx.z;
    const int cnt = counts[e];
    const int m0 = blockIdx.x * 64;
    if (m0 >= cnt) return;
    const int n0 = blockIdx.y * 64;
    const int off_e = offs[e];

    __shared__ unsigned short As[64 * 40];
    __shared__ unsigned short Bs[64 * 40];

    const int tid = threadIdx.x;
    const int r = tid >> 2;
    const int seg = tid & 3;

    const unsigned short* aptr = hbuf + (size_t)(off_e + m0 + r) * I_DIM + seg * 8;
    const float* bptr = w2 + ((size_t)e * H_DIM + n0 + r) * I_DIM + seg * 8;

    const int lane = tid & 63;
    const int wv = tid >> 6;
    const int wm = (wv >> 1) * 32;
    const int wn = (wv & 1) * 32;
    const int lm = lane & 15;
    const int quad = lane >> 4;
    const int koff = quad * 8;

    f32x4 acc[2][2];
    for (int i = 0; i < 2; i++)
        for (int j = 0; j < 2; j++) acc[i][j] = (f32x4)(0.f);

    for (int k0 = 0; k0 < I_DIM; k0 += 32) {
        *(uint4*)&As[r * 40 + seg * 8] = *(const uint4*)(aptr + k0);
        float4 f0 = *(const float4*)(bptr + k0);
        float4 f1 = *(const float4*)(bptr + k0 + 4);
        *(uint4*)&Bs[r * 40 + seg * 8] = pack8(f0, f1);
        __syncthreads();

        bf16x8 af[2], bf[2];
        for (int ms = 0; ms < 2; ms++)
            af[ms] = *(const bf16x8*)&As[(wm + ms * 16 + lm) * 40 + koff];
        for (int ns = 0; ns < 2; ns++)
            bf[ns] = *(const bf16x8*)&Bs[(wn + ns * 16 + lm) * 40 + koff];
        for (int ms = 0; ms < 2; ms++)
            for (int ns = 0; ns < 2; ns++)
                acc[ms][ns] = __builtin_amdgcn_mfma_f32_16x16x32_bf16(af[ms], bf[ns], acc[ms][ns], 0, 0, 0);
        __syncthreads();
    }

    for (int ms = 0; ms < 2; ms++)
        for (int rg = 0; rg < 4; rg++) {
            int row = wm + ms * 16 + quad * 4 + rg;
            int i = m0 + row;
            if (i < cnt) {
                int tok = list_idx[e * T_DIM + i];
                float wt = list_wt[e * T_DIM + i];
                for (int ns = 0; ns < 2; ns++) {
                    int j = n0 + wn + ns * 16 + lm;
                    float v = acc[ms][ns][rg] + b2[e * H_DIM + j];
                    atomicAdd(&y[(size_t)tok * H_DIM + j], wt * v);
                }
            }
        }
}

extern "C" void kernel_launch(void* const* d_in, const int* in_sizes, int n_in,
                              void* d_out, int out_size, void* d_ws, size_t ws_size,
                              hipStream_t stream) {
    const float* x  = (const float*)d_in[0];
    const float* rw = (const float*)d_in[1];
    const float* rb = (const float*)d_in[2];
    const float* w1 = (const float*)d_in[3];
    const float* b1 = (const float*)d_in[4];
    const float* w3 = (const float*)d_in[5];
    const float* b3 = (const float*)d_in[6];
    const float* w2 = (const float*)d_in[7];
    const float* b2 = (const float*)d_in[8];
    float* y = (float*)d_out;

    char* ws = (char*)d_ws;
    unsigned short* xb = (unsigned short*)(ws + XB_OFF);
    int* list_idx     = (int*)(ws + LIDX_OFF);
    float* list_wt    = (float*)(ws + LWT_OFF);
    int* counts       = (int*)(ws + CNT_OFF);
    int* offs         = (int*)(ws + OFF_OFF);
    unsigned short* hbuf = (unsigned short*)(ws + HBUF_OFF);

    hipMemsetAsync(counts, 0, E_NUM * sizeof(int), stream);
    hipMemsetAsync(d_out, 0, (size_t)out_size * sizeof(float), stream);

    router_kernel<<<T_DIM, 256, 0, stream>>>(x, rw, rb, list_idx, list_wt, counts);
    offsets_kernel<<<1, 64, 0, stream>>>(counts, offs);
    cvt_kernel<<<(T_DIM * H_DIM / 4) / 256, 256, 0, stream>>>((const float4*)x, (uint2*)xb);
    gemm1_kernel<<<dim3(16, 45, E_NUM), 256, 0, stream>>>(xb, w1, b1, w3, b3, list_idx, counts, offs, hbuf);
    gemm2_kernel<<<dim3(16, 45, E_NUM), 256, 0, stream>>>(hbuf, w2, b2, list_idx, list_wt, counts, offs, y);
}